// Round 15
// baseline (87.483 us; speedup 1.0000x reference)
//
#include <hip/hip_runtime.h>
#include <hip/hip_bf16.h>

#define L_CLS 2048
#define D_DIM 512
#define T_SZ  512
#define NT    511              // T-1 transitions per sequence
#define NOUT  (64 * NT)        // 32704
#define NCHUNK 16              // 128-col chunks
#define LDSS  136              // LDS row stride in elems (272 B)
#define LOG2E 1.4426950408889634f
#define LN2   0.6931471805599453f
#define SHIFT 128.0f           // fixed exponent shift: sum 2^(x*log2e - SHIFT)

typedef __attribute__((ext_vector_type(8))) short bf16x8;
typedef __attribute__((ext_vector_type(4))) float f32x4;

static __device__ __forceinline__ short f2bf(float x) {
    return (short)__bfloat16_as_ushort(__float2bfloat16(x));
}

// MEASUREMENT ROUND: R12 structure (best: 27.6us) with in-kernel iters repeat
// (idempotent) so each kernel becomes one LONG dispatch that outranks the
// ~40us fillBuffer poison dispatches in rocprof top-5. gemm x8, conv x16,
// gather x16. dur/iter + per-kernel counters finally become visible.

// ---------------------------------------------------------------- conv kernel
__global__ void conv_bf16(const float* __restrict__ srcE, const float* __restrict__ tgtE,
                          __hip_bfloat16* __restrict__ Sb, __hip_bfloat16* __restrict__ Tb,
                          int iters) {
    int i = blockIdx.x * blockDim.x + threadIdx.x;   // groups of 8
    if (i >= (L_CLS * D_DIM) / 8) return;
#pragma unroll 1
    for (int it = 0; it < iters; ++it) {
        const f32x4* s4 = reinterpret_cast<const f32x4*>(srcE) + i * 2;
        const f32x4* t4 = reinterpret_cast<const f32x4*>(tgtE) + i * 2;
        f32x4 s0 = s4[0], s1 = s4[1];
        f32x4 t0 = t4[0], t1 = t4[1];
        bf16x8 so, to;
#pragma unroll
        for (int j = 0; j < 4; ++j) {
            so[j] = f2bf(s0[j]); so[j + 4] = f2bf(s1[j]);
            to[j] = f2bf(t0[j]); to[j + 4] = f2bf(t1[j]);
        }
        reinterpret_cast<bf16x8*>(Sb)[i] = so;
        reinterpret_cast<bf16x8*>(Tb)[i] = to;
    }
}

// --------------------------------------------------- bf16 GEMM + exp-sums + M
// R12 structure exactly: grid (16,16) x 512 thr (8 waves), wave = 16 rows x
// 128 cols, reg-staged B + prefetch, 2 barriers/slice.
__launch_bounds__(512)
__global__ void gemm_lse_bf16(const __hip_bfloat16* __restrict__ Sb,
                              const __hip_bfloat16* __restrict__ Tb,
                              float* __restrict__ psum,
                              float* __restrict__ M, int iters) {
    __shared__ __hip_bfloat16 Blds[128 * LDSS];   // 34816 B

    const int tid  = threadIdx.x;
    const int wave = tid >> 6;           // 0..7
    const int lane = tid & 63;
    const int lr   = lane & 15;
    const int hi   = lane >> 4;
    const int C    = blockIdx.x * 128;
    const int R    = blockIdx.y * 128 + wave * 16;

#pragma unroll 1
    for (int it = 0; it < iters; ++it) {
        f32x4 acc[8];
#pragma unroll
        for (int ct = 0; ct < 8; ++ct) acc[ct] = (f32x4){0.f, 0.f, 0.f, 0.f};

        bf16x8 stg[4], an[4];
#pragma unroll
        for (int i = 0; i < 4; ++i) {
            int p = tid + 512 * i;           // 0..2047
            stg[i] = *reinterpret_cast<const bf16x8*>(
                &Tb[(C + (p >> 4)) * D_DIM + (p & 15) * 8]);
        }
#pragma unroll
        for (int ks = 0; ks < 4; ++ks)
            an[ks] = *reinterpret_cast<const bf16x8*>(
                &Sb[(R + lr) * D_DIM + ks * 32 + hi * 8]);

#pragma unroll 1
        for (int s = 0; s < 4; ++s) {
#pragma unroll
            for (int i = 0; i < 4; ++i) {
                int p = tid + 512 * i;
                *reinterpret_cast<bf16x8*>(&Blds[(p >> 4) * LDSS + (p & 15) * 8]) = stg[i];
            }
            bf16x8 a[4];
#pragma unroll
            for (int ks = 0; ks < 4; ++ks) a[ks] = an[ks];
            __syncthreads();

            if (s < 3) {   // prefetch next slice under the MFMAs
#pragma unroll
                for (int i = 0; i < 4; ++i) {
                    int p = tid + 512 * i;
                    stg[i] = *reinterpret_cast<const bf16x8*>(
                        &Tb[(C + (p >> 4)) * D_DIM + (s + 1) * 128 + (p & 15) * 8]);
                }
#pragma unroll
                for (int ks = 0; ks < 4; ++ks)
                    an[ks] = *reinterpret_cast<const bf16x8*>(
                        &Sb[(R + lr) * D_DIM + (s + 1) * 128 + ks * 32 + hi * 8]);
            }

#pragma unroll
            for (int ks = 0; ks < 4; ++ks) {
                const int off = ks * 32 + hi * 8;
#pragma unroll
                for (int ct = 0; ct < 8; ++ct) {
                    bf16x8 b = *reinterpret_cast<const bf16x8*>(
                        &Blds[(ct * 16 + lr) * LDSS + off]);
                    acc[ct] = __builtin_amdgcn_mfma_f32_16x16x32_bf16(a[ks], b, acc[ct], 0, 0, 0);
                }
            }
            __syncthreads();
        }

        // ---- epilogue: M writes + fixed-shift exp sums ----
#pragma unroll
        for (int i = 0; i < 4; ++i) {
            size_t rg = (size_t)(R + hi * 4 + i) * L_CLS + C + lr;
#pragma unroll
            for (int ct = 0; ct < 8; ++ct)
                M[rg + ct * 16] = acc[ct][i];
        }
        float p[4];
#pragma unroll
        for (int i = 0; i < 4; ++i) {
            p[i] = 0.f;
#pragma unroll
            for (int ct = 0; ct < 8; ++ct)
                p[i] += exp2f(acc[ct][i] * LOG2E - SHIFT);
        }
#pragma unroll
        for (int off = 1; off < 16; off <<= 1)
#pragma unroll
            for (int i = 0; i < 4; ++i) p[i] += __shfl_xor(p[i], off);
        if (lr == 0) {
#pragma unroll
            for (int i = 0; i < 4; ++i)
                psum[(R + hi * 4 + i) * NCHUNK + blockIdx.x] = p[i];
        }
    }
}

// -------------------------------------------------------------- gather scores
__launch_bounds__(256)
__global__ void scores_gather(const int* __restrict__ labels,
                              const float* __restrict__ psum,
                              const float* __restrict__ M,
                              float* __restrict__ out, int iters) {
    int o = blockIdx.x * 256 + threadIdx.x;
    if (o >= NOUT) return;
#pragma unroll 1
    for (int it = 0; it < iters; ++it) {
        int b = o / NT;
        int t = o - b * NT;
        int src = labels[b * T_SZ + t];
        int tgt = labels[b * T_SZ + t + 1];

        const f32x4* pv = reinterpret_cast<const f32x4*>(psum + src * NCHUNK);
        f32x4 s0 = pv[0], s1 = pv[1], s2 = pv[2], s3 = pv[3];
        float S = (s0[0]+s0[1]+s0[2]+s0[3]) + (s1[0]+s1[1]+s1[2]+s1[3])
                + (s2[0]+s2[1]+s2[2]+s2[3]) + (s3[0]+s3[1]+s3[2]+s3[3]);
        float lse = (log2f(S) + SHIFT) * LN2;
        out[o] = M[(size_t)src * L_CLS + tgt] - lse;
    }
}

// ------------------------------------------------------------------- launcher
extern "C" void kernel_launch(void* const* d_in, const int* in_sizes, int n_in,
                              void* d_out, int out_size, void* d_ws, size_t ws_size,
                              hipStream_t stream) {
    const int*   labels = (const int*)d_in[0];
    const float* srcE   = (const float*)d_in[1];
    const float* tgtE   = (const float*)d_in[2];
    float*       out    = (float*)d_out;

    const size_t tbl = (size_t)L_CLS * D_DIM;
    __hip_bfloat16* Sb = (__hip_bfloat16*)d_ws;                    // 2 MB
    __hip_bfloat16* Tb = Sb + tbl;                                 // 2 MB
    float* psum = (float*)((char*)d_ws + 2 * tbl * sizeof(__hip_bfloat16)); // 128 KB
    float* M    = psum + (size_t)L_CLS * NCHUNK;                   // 16 MB

    conv_bf16<<<(int)(tbl / 8 + 255) / 256, 256, 0, stream>>>(srcE, tgtE, Sb, Tb, 16);
    gemm_lse_bf16<<<dim3(NCHUNK, 16), 512, 0, stream>>>(Sb, Tb, psum, M, 8);
    scores_gather<<<(NOUT + 255) / 256, 256, 0, stream>>>(labels, psum, M, out, 16);
}

// Round 16
// 28.231 us; speedup vs baseline: 3.0989x; 3.0989x over previous
//
#include <hip/hip_runtime.h>
#include <hip/hip_bf16.h>

#define L_CLS 2048
#define D_DIM 512
#define T_SZ  512
#define NT    511              // T-1 transitions per sequence
#define NOUT  (64 * NT)        // 32704
#define NCHUNK 32              // 64-col chunks
#define LOG2E 1.4426950408889634f
#define LN2   0.6931471805599453f
#define SHIFT 128.0f           // fixed exponent shift: sum 2^(x*log2e - SHIFT)

typedef __attribute__((ext_vector_type(8))) short bf16x8;
typedef __attribute__((ext_vector_type(4))) float f32x4;

static __device__ __forceinline__ short f2bf(float x) {
    return (short)__bfloat16_as_ushort(__float2bfloat16(x));
}

// ---------------------------------------------------------------- conv kernel
__global__ void conv_bf16(const float* __restrict__ srcE, const float* __restrict__ tgtE,
                          __hip_bfloat16* __restrict__ Sb, __hip_bfloat16* __restrict__ Tb) {
    int i = blockIdx.x * blockDim.x + threadIdx.x;   // groups of 8
    if (i >= (L_CLS * D_DIM) / 8) return;
    const f32x4* s4 = reinterpret_cast<const f32x4*>(srcE) + i * 2;
    const f32x4* t4 = reinterpret_cast<const f32x4*>(tgtE) + i * 2;
    f32x4 s0 = s4[0], s1 = s4[1];
    f32x4 t0 = t4[0], t1 = t4[1];
    bf16x8 so, to;
#pragma unroll
    for (int j = 0; j < 4; ++j) {
        so[j] = f2bf(s0[j]); so[j + 4] = f2bf(s1[j]);
        to[j] = f2bf(t0[j]); to[j + 4] = f2bf(t1[j]);
    }
    reinterpret_cast<bf16x8*>(Sb)[i] = so;
    reinterpret_cast<bf16x8*>(Tb)[i] = to;
}

// ------------------------------------- bf16 GEMM + exp-sums + M (swizzled) --
// grid (32,16) x 512 thr = 512 WGs -> 2 WGs/CU (R15 measured: 256 WGs = 1/CU,
// Occupancy 20%, grid-limited). Wave w: rows by*128 + w*16, cols bx*64.
// LDS B-tile: 64 rows x 128 k bf16, LINEAR 256B rows + XOR swizzle
// (elem c8 ^= (row&7)<<3) -- the guide-verified fix for per-row ds_read_b128
// bank conflicts (R15 measured 8.4M conflicts with pad-272; pad does NOT fix
// this pattern). Same swizzle applied on write and read.
__launch_bounds__(512, 4)
__global__ void gemm_lse_bf16(const __hip_bfloat16* __restrict__ Sb,
                              const __hip_bfloat16* __restrict__ Tb,
                              float* __restrict__ psum,
                              float* __restrict__ M) {
    __shared__ __hip_bfloat16 Blds[64 * 128];   // 16384 B, linear + XOR

    const int tid  = threadIdx.x;
    const int wave = tid >> 6;           // 0..7
    const int lane = tid & 63;
    const int lr   = lane & 15;
    const int hi   = lane >> 4;
    const int C    = blockIdx.x * 64;
    const int R    = blockIdx.y * 128 + wave * 16;

    f32x4 acc[4];
#pragma unroll
    for (int ct = 0; ct < 4; ++ct) acc[ct] = (f32x4){0.f, 0.f, 0.f, 0.f};

    bf16x8 stg[2], an[4];
    // prologue: slice 0 B-chunk + A-frags into regs
#pragma unroll
    for (int i = 0; i < 2; ++i) {
        int p = tid + 512 * i;           // 0..1023: row p>>4, 16B-chunk p&15
        stg[i] = *reinterpret_cast<const bf16x8*>(
            &Tb[(C + (p >> 4)) * D_DIM + (p & 15) * 8]);
    }
#pragma unroll
    for (int ks = 0; ks < 4; ++ks)
        an[ks] = *reinterpret_cast<const bf16x8*>(
            &Sb[(R + lr) * D_DIM + ks * 32 + hi * 8]);

#pragma unroll 1
    for (int s = 0; s < 4; ++s) {
        // ds_write staged B chunk (XOR-swizzled slot within each 256B row)
#pragma unroll
        for (int i = 0; i < 2; ++i) {
            int p   = tid + 512 * i;
            int row = p >> 4;
            int e   = (p & 15) * 8;
            *reinterpret_cast<bf16x8*>(
                &Blds[row * 128 + (e ^ ((row & 7) << 3))]) = stg[i];
        }
        bf16x8 a[4];
#pragma unroll
        for (int ks = 0; ks < 4; ++ks) a[ks] = an[ks];
        __syncthreads();

        if (s < 3) {   // prefetch next slice under the MFMAs
#pragma unroll
            for (int i = 0; i < 2; ++i) {
                int p = tid + 512 * i;
                stg[i] = *reinterpret_cast<const bf16x8*>(
                    &Tb[(C + (p >> 4)) * D_DIM + (s + 1) * 128 + (p & 15) * 8]);
            }
#pragma unroll
            for (int ks = 0; ks < 4; ++ks)
                an[ks] = *reinterpret_cast<const bf16x8*>(
                    &Sb[(R + lr) * D_DIM + (s + 1) * 128 + ks * 32 + hi * 8]);
        }

#pragma unroll
        for (int ks = 0; ks < 4; ++ks) {
#pragma unroll
            for (int ct = 0; ct < 4; ++ct) {
                int row = ct * 16 + lr;
                int e   = (ks * 32 + hi * 8) ^ ((lr & 7) << 3);
                bf16x8 b = *reinterpret_cast<const bf16x8*>(&Blds[row * 128 + e]);
                acc[ct] = __builtin_amdgcn_mfma_f32_16x16x32_bf16(a[ks], b, acc[ct], 0, 0, 0);
            }
        }
        __syncthreads();
    }

    // ---- epilogue: M writes + fixed-shift exp sums ----
    // D layout: col = C + ct*16 + lr, row = R + hi*4 + i.
#pragma unroll
    for (int i = 0; i < 4; ++i) {
        size_t rg = (size_t)(R + hi * 4 + i) * L_CLS + C + lr;
#pragma unroll
        for (int ct = 0; ct < 4; ++ct)
            M[rg + ct * 16] = acc[ct][i];
    }
    float p[4];
#pragma unroll
    for (int i = 0; i < 4; ++i) {
        p[i] = 0.f;
#pragma unroll
        for (int ct = 0; ct < 4; ++ct)
            p[i] += exp2f(acc[ct][i] * LOG2E - SHIFT);
    }
#pragma unroll
    for (int off = 1; off < 16; off <<= 1)
#pragma unroll
        for (int i = 0; i < 4; ++i) p[i] += __shfl_xor(p[i], off);
    if (lr == 0) {
#pragma unroll
        for (int i = 0; i < 4; ++i)
            psum[(R + hi * 4 + i) * NCHUNK + blockIdx.x] = p[i];
    }
}

// -------------------------------------------------------------- gather scores
__launch_bounds__(256)
__global__ void scores_gather(const int* __restrict__ labels,
                              const float* __restrict__ psum,
                              const float* __restrict__ M,
                              float* __restrict__ out) {
    int o = blockIdx.x * 256 + threadIdx.x;
    if (o >= NOUT) return;
    int b = o / NT;
    int t = o - b * NT;
    int src = labels[b * T_SZ + t];
    int tgt = labels[b * T_SZ + t + 1];

    const f32x4* pv = reinterpret_cast<const f32x4*>(psum + src * NCHUNK);
    f32x4 sv = pv[0];
#pragma unroll
    for (int c = 1; c < NCHUNK / 4; ++c) {
        f32x4 v = pv[c];
        sv[0] += v[0]; sv[1] += v[1]; sv[2] += v[2]; sv[3] += v[3];
    }
    float S = (sv[0] + sv[1]) + (sv[2] + sv[3]);
    float lse = (log2f(S) + SHIFT) * LN2;
    out[o] = M[(size_t)src * L_CLS + tgt] - lse;
}

// ------------------------------------------------------------------- launcher
extern "C" void kernel_launch(void* const* d_in, const int* in_sizes, int n_in,
                              void* d_out, int out_size, void* d_ws, size_t ws_size,
                              hipStream_t stream) {
    const int*   labels = (const int*)d_in[0];
    const float* srcE   = (const float*)d_in[1];
    const float* tgtE   = (const float*)d_in[2];
    float*       out    = (float*)d_out;

    const size_t tbl = (size_t)L_CLS * D_DIM;
    __hip_bfloat16* Sb = (__hip_bfloat16*)d_ws;                    // 2 MB
    __hip_bfloat16* Tb = Sb + tbl;                                 // 2 MB
    float* psum = (float*)((char*)d_ws + 2 * tbl * sizeof(__hip_bfloat16)); // 256 KB
    float* M    = psum + (size_t)L_CLS * NCHUNK;                   // 16 MB

    conv_bf16<<<(int)(tbl / 8 + 255) / 256, 256, 0, stream>>>(srcE, tgtE, Sb, Tb);
    gemm_lse_bf16<<<dim3(NCHUNK, 16), 512, 0, stream>>>(Sb, Tb, psum, M);
    scores_gather<<<(NOUT + 255) / 256, 256, 0, stream>>>(labels, psum, M, out);
}